// Round 13
// baseline (135.738 us; speedup 1.0000x reference)
//
#include <hip/hip_runtime.h>

// ForwardKinematics fp32: rotations (B,24,4) wxyz + positions (B,24,3)
// -> global joint positions (B,24,3). Fixed SMPL tree.
//
// Round 17: r16 + RAW BARRIERS + DEPTH-2 PREFETCH (T3/T4 port).
//  - Mechanism: __syncthreads() lowers to s_waitcnt vmcnt(0) lgkmcnt(0)
//    + s_barrier (m97 finding) -> every gen force-drains the 11 fresh
//    prefetch loads (~900cy exposed; scatter consumed them only ~25
//    instrs after issue) and the 5 stores. Fix per the 8-phase GEMM
//    template: __builtin_amdgcn_s_barrier() (NO forced vmcnt drain) +
//    explicit s_waitcnt lgkmcnt(0) for LDS visibility; loads issued in
//    gen i are consumed in gen i+1 (full-gen flight time) so the
//    compiler's automatic dependence wait becomes vmcnt(16) == free,
//    and loads/stores pipeline ACROSS barriers (one-gen store lag).
//  - Depth-2 staging sets A/B are STATIC (rule #20): gen loop unrolled
//    x2 with compile-time buffer indices and set roles.
//  - (512,1): VGPR cap 256 (arg2 = min blocks/CU vs 2048-reg pool,
//    r14 model); ~160 live (88 staging + compute branch) -> no spill.
//    LDS 123KB already caps at 1 block/CU, so arg2=1 costs nothing.
//  - Everything else = r16 (verified): 4 compute + 4 mem waves, SPB=64,
//    GRIDP=256 persistent, disjoint-array handoff, cached stores.

typedef float f32x4 __attribute__((ext_vector_type(4)));

struct M { float r0,r1,r2,r3,r4,r5,r6,r7,r8,tx,ty,tz; };

__device__ __forceinline__ M loc(float a, float b, float c, float d,
                                 float px, float py, float pz) {
    float inv = rsqrtf(a*a + b*b + c*c + d*d);
    float qw = a*inv, qx = b*inv, qy = c*inv, qz = d*inv;
    float x2 = qx+qx, y2 = qy+qy, z2 = qz+qz;
    float xx = qx*x2, yy = qy*y2, zz = qz*z2;
    float xy = qx*y2, yz = qy*z2, xz = qx*z2;
    float wx = qw*x2, wy = qw*y2, wz = qw*z2;
    M m;
    m.r0 = 1.f-(yy+zz); m.r1 = xy-wz;       m.r2 = xz+wy;
    m.r3 = xy+wz;       m.r4 = 1.f-(xx+zz); m.r5 = yz-wx;
    m.r6 = xz-wy;       m.r7 = yz+wx;       m.r8 = 1.f-(xx+yy);
    m.tx = px; m.ty = py; m.tz = pz;
    return m;
}

__device__ __forceinline__ M mul(const M& a, const M& b) {
    M c;
    c.r0 = a.r0*b.r0 + a.r1*b.r3 + a.r2*b.r6;
    c.r1 = a.r0*b.r1 + a.r1*b.r4 + a.r2*b.r7;
    c.r2 = a.r0*b.r2 + a.r1*b.r5 + a.r2*b.r8;
    c.r3 = a.r3*b.r0 + a.r4*b.r3 + a.r5*b.r6;
    c.r4 = a.r3*b.r1 + a.r4*b.r4 + a.r5*b.r7;
    c.r5 = a.r3*b.r2 + a.r4*b.r5 + a.r5*b.r8;
    c.r6 = a.r6*b.r0 + a.r7*b.r3 + a.r8*b.r6;
    c.r7 = a.r6*b.r1 + a.r7*b.r4 + a.r8*b.r7;
    c.r8 = a.r6*b.r2 + a.r7*b.r5 + a.r8*b.r8;
    c.tx = a.r0*b.tx + a.r1*b.ty + a.r2*b.tz + a.tx;
    c.ty = a.r3*b.tx + a.r4*b.ty + a.r5*b.tz + a.ty;
    c.tz = a.r6*b.tx + a.r7*b.ty + a.r8*b.tz + a.tz;
    return c;
}

#define SPB    64
#define NTHR   512
#define GRIDP  256   // persistent blocks: 1 per CU
#define RPITCH 100   // 16B-aligned quat rows -> ds_read_b128
#define PPITCH 73    // odd -> conflict-free b32 access

// Wave-uniform 4-way tree split (verified rounds 7-16).
constexpr int MT0[6]  = {0,1,2,4,7,10};
constexpr int PR0[6]  = {-1,0,0,1,3,4};
constexpr int MT1[8]  = {0,2,5,8,11,3,6,9};
constexpr int PR1[8]  = {-1,0,1,2,3,0,5,6};
constexpr int MT2[11] = {0,3,6,9,12,15,13,16,18,20,22};
constexpr int PR2[11] = {-1,0,1,2,3,4,3,6,7,8,9};
constexpr int MT3[9]  = {0,3,6,9,14,17,19,21,23};
constexpr int PR3[9]  = {-1,0,1,2,3,4,5,6,7};

template<int NM>
__device__ __forceinline__ void run_chain(const int (&MT)[NM], const int (&PR)[NM],
                                          int WS,
                                          const float* __restrict__ R,
                                          const float* __restrict__ P,
                                          float* __restrict__ O) {
    M G[NM];
    {
        f32x4 q = *(const f32x4*)(R);
        G[0] = loc(q.x, q.y, q.z, q.w, P[0], P[1], P[2]);
    }
    if (WS == 0) { O[0]=G[0].tx; O[1]=G[0].ty; O[2]=G[0].tz; }
#pragma unroll
    for (int k = 1; k < NM; ++k) {
        const int j = MT[k];
        f32x4 q = *(const f32x4*)(R + 4*j);
        M L = loc(q.x, q.y, q.z, q.w, P[3*j], P[3*j+1], P[3*j+2]);
        G[k] = mul(G[PR[k]], L);
        if (k >= WS) { O[3*j]=G[k].tx; O[3*j+1]=G[k].ty; O[3*j+2]=G[k].tz; }
    }
}

// ---- memory-wave helpers (mt in [0,256)) ----
__device__ __forceinline__ void load_regs(int c, int mt,
                                          const float* __restrict__ rot,
                                          const float* __restrict__ pos,
                                          size_t limR, size_t limP,
                                          f32x4 (&vr)[6], f32x4 (&vp)[5]) {
    const size_t baseR = (size_t)c * (SPB*96);   // 6144 dw/chunk
    const size_t baseP = (size_t)c * (SPB*72);   // 4608 dw/chunk
#pragma unroll
    for (int i = 0; i < 6; ++i) {
        const size_t gi = baseR + (size_t)(i*1024 + 4*mt);
        f32x4 v = {0.f,0.f,0.f,0.f};
        if (gi < limR) v = *(const f32x4*)(rot + gi);
        vr[i] = v;
    }
#pragma unroll
    for (int i = 0; i < 5; ++i) {
        const bool g = (i < 4) || (mt < 128);
        const size_t gi = baseP + (size_t)(i*1024 + 4*mt);
        f32x4 v = {0.f,0.f,0.f,0.f};
        if (g && gi < limP) v = *(const f32x4*)(pos + gi);
        vp[i] = v;
    }
}

__device__ __forceinline__ void scatter_lds(int mt,
                                            float* __restrict__ Rb,
                                            float* __restrict__ Pb,
                                            const f32x4 (&vr)[6],
                                            const f32x4 (&vp)[5]) {
#pragma unroll
    for (int i = 0; i < 6; ++i) {
        const int f = i*1024 + 4*mt;
        const int s = f / 96, r = f - 96*s;
        *(f32x4*)(Rb + s*RPITCH + r) = vr[i];     // aligned b128 write
    }
#pragma unroll
    for (int i = 0; i < 5; ++i) {
        if ((i < 4) || (mt < 128)) {
            const int f = i*1024 + 4*mt;
            const int s = f / 72, r = f - 72*s;
            float* d = Pb + s*PPITCH + r;
            d[0]=vp[i].x; d[1]=vp[i].y; d[2]=vp[i].z; d[3]=vp[i].w;
        }
    }
}

__device__ __forceinline__ void store_chunk(const float* __restrict__ Ob,
                                            int c, int mt, size_t limP,
                                            float* __restrict__ out) {
    const size_t baseO = (size_t)c * (SPB*72);
#pragma unroll
    for (int n = 0; n < 5; ++n) {
        if ((n < 4) || (mt < 128)) {
            const int F = n*1024 + 4*mt;
            const int s = F / 72, r = F - 72*s;
            const size_t gi = baseO + (size_t)F;
            if (gi < limP) {
                f32x4 v = { Ob[s*PPITCH+r+0], Ob[s*PPITCH+r+1],
                            Ob[s*PPITCH+r+2], Ob[s*PPITCH+r+3] };
                *(f32x4*)(out + gi) = v;   // cached: full-line, no RFO
            }
        }
    }
}

__device__ __forceinline__ void lgkm_fence_barrier() {
    // LDS visibility only; deliberately NO vmcnt drain (loads/stores
    // keep flying across the barrier -- the whole point of this round).
    asm volatile("s_waitcnt lgkmcnt(0)" ::: "memory");
    __builtin_amdgcn_s_barrier();
}

__global__ __launch_bounds__(NTHR, 1) void fk_kernel(
    const float* __restrict__ rot,   // B*96 floats (quat wxyz per joint)
    const float* __restrict__ pos,   // B*72 floats
    float*       __restrict__ out,   // B*72 floats
    int B)
{
    __shared__ __align__(16) float ldsR[2][SPB * RPITCH];  // 2 x 25600 B
    __shared__ float ldsP[2][SPB * PPITCH];                // 2 x 18688 B
    __shared__ float ldsO[2][SPB * PPITCH];                // 2 x 18688 B

    const int t   = threadIdx.x;
    const int w   = t >> 6;
    const bool cw = (w < 4);          // compute waves 0..3, mem waves 4..7
    const int mt  = t & 255;
    const int nch = (B + SPB - 1) / SPB;
    const size_t limR = (size_t)B * 96;
    const size_t limP = (size_t)B * 72;
    const int c0  = blockIdx.x;

    f32x4 vrA[6], vpA[5];            // staging set A (static names, rule #20)
    f32x4 vrB[6], vpB[5];            // staging set B

    // ---- prologue: buf0 <- chunk c0 (via B); A <- chunk c0+G (in flight) ----
    if (!cw) {
        if (c0 < nch) {
            load_regs(c0, mt, rot, pos, limR, limP, vrB, vpB);
            scatter_lds(mt, ldsR[0], ldsP[0], vrB, vpB);  // auto vmcnt wait
        }
        if (c0 + GRIDP < nch)
            load_regs(c0 + GRIDP, mt, rot, pos, limR, limP, vrA, vpA);
    }
    lgkm_fence_barrier();            // A's loads stay in flight into gen 0

    // ---- gen loop, unrolled x2 for static buffer/set roles ----
    // Gen (c, Q, P=prev set, N=next set):
    //   compute: chains chunk c from buf Q -> ldsO[Q]
    //   mem:     issue loads c+2G -> N; store c-G from ldsO[Q^1];
    //            scatter P (chunk c+G) -> buf Q^1   [auto vmcnt(16)]
    //   lgkm fence + raw barrier
#define FK_GEN(c_, Q_, VRP, VPP, VRN, VPN)                                   \
    {                                                                        \
        if (cw) {                                                            \
            const int l = t & 63;                                            \
            const int b = (c_) * SPB + l;                                    \
            if (b < B) {                                                     \
                const float* R = &ldsR[Q_][l * RPITCH];                      \
                const float* P = &ldsP[Q_][l * PPITCH];                      \
                float*       O = &ldsO[Q_][l * PPITCH];                      \
                switch (w) {                                                 \
                    case 0:  run_chain(MT0, PR0, 0, R, P, O); break;         \
                    case 1:  run_chain(MT1, PR1, 2, R, P, O); break;         \
                    case 2:  run_chain(MT2, PR2, 4, R, P, O); break;         \
                    default: run_chain(MT3, PR3, 4, R, P, O); break;         \
                }                                                            \
            }                                                                \
        } else {                                                             \
            if ((c_) + 2*GRIDP < nch)                                        \
                load_regs((c_) + 2*GRIDP, mt, rot, pos, limR, limP, VRN, VPN);\
            if ((c_) > c0)                                                   \
                store_chunk(ldsO[(Q_)^1], (c_) - GRIDP, mt, limP, out);      \
            if ((c_) + GRIDP < nch)                                          \
                scatter_lds(mt, ldsR[(Q_)^1], ldsP[(Q_)^1], VRP, VPP);       \
        }                                                                    \
        lgkm_fence_barrier();                                                \
    }

    int c = c0;
    while (c < nch) {
        FK_GEN(c, 0, vrA, vpA, vrB, vpB);
        c += GRIDP;
        if (c >= nch) break;
        FK_GEN(c, 1, vrB, vpB, vrA, vpA);
        c += GRIDP;
    }
#undef FK_GEN

    // ---- epilogue: store final chunk's outputs ----
    if (!cw && c > c0) {
        const int lastq = (((c - c0) / GRIDP) - 1) & 1;
        store_chunk(ldsO[lastq], c - GRIDP, mt, limP, out);
    }
}

extern "C" void kernel_launch(void* const* d_in, const int* in_sizes, int n_in,
                              void* d_out, int out_size, void* d_ws, size_t ws_size,
                              hipStream_t stream) {
    const int B = out_size / 72;           // (B,24,3)
    const void* rot = nullptr;
    const void* pos = nullptr;
    for (int i = 0; i < n_in; ++i) {       // resolve by size, not order
        if      (in_sizes[i] == B * 96) rot = d_in[i];
        else if (in_sizes[i] == B * 72) pos = d_in[i];
    }
    if (!rot) rot = d_in[2];
    if (!pos) pos = d_in[1];

    const int nch  = (B + SPB - 1) / SPB;  // 2048 chunks @ B=131072
    const int grid = (nch < GRIDP) ? nch : GRIDP;
    fk_kernel<<<grid, NTHR, 0, stream>>>(
        (const float*)rot, (const float*)pos, (float*)d_out, B);
}